// Round 8
// baseline (149.404 us; speedup 1.0000x reference)
//
#include <hip/hip_runtime.h>

#define B_ 8
#define CIN 64
#define COUT 64
#define H_ 128
#define W_ 128
#define HW (H_*W_)
#define OFFP 24   // shorts per pixel in St/offb (9 taps * 2 + pad -> 48B)

typedef __attribute__((ext_vector_type(8))) short short8;   // 8 bf16 (4 VGPRs)
typedef __attribute__((ext_vector_type(4))) short s16x4;    // 4 shorts
typedef __attribute__((ext_vector_type(4))) float f32x4;    // MFMA acc / weights
typedef __attribute__((ext_vector_type(2))) float f32x2;    // packed-FMA pair

__device__ __forceinline__ short f2bf(float f) {
    unsigned u = __float_as_uint(f);
    unsigned r = (u + 0x7fffu + ((u >> 16) & 1u)) >> 16;   // RNE
    return (short)r;
}
__device__ __forceinline__ float bf2f(short s) {
    return __uint_as_float(((unsigned)(unsigned short)s) << 16);
}

// ---------- weight prep: -> lane-linear bf16 frags ----------
template<int NT>
__device__ __forceinline__ void prep_one(const float* __restrict__ w, short* __restrict__ o,
                                         int i, int n_used) {
    int j = i & 7, lane = (i >> 3) & 63, rest = i >> 9;
    int nt = rest % NT, dc = rest / NT, c = dc & 1, d = dc >> 1;
    int oc = nt * 16 + (lane & 15);
    int ic = c * 32 + (lane >> 4) * 8 + j;
    float v = (oc < n_used) ? w[(oc * 64 + ic) * 9 + d] : 0.f;
    o[i] = f2bf(v);
}

// ---------- transpose x NCHW fp32 -> NHWC bf16, + weight prep folded in ----------
__global__ __launch_bounds__(256) void k_tr(const float* __restrict__ x,
                                            short* __restrict__ xt,
                                            const float* __restrict__ wof,
                                            const float* __restrict__ wrg,
                                            short* __restrict__ wt1,
                                            short* __restrict__ wt2) {
    int i = blockIdx.x * 256 + threadIdx.x;
    if (i < 9 * 2 * 2 * 512) prep_one<2>(wof, wt1, i, 18);
    if (i < 9 * 2 * 4 * 512) prep_one<4>(wrg, wt2, i, 64);

    __shared__ float tile[64 * 129];
    int bh = blockIdx.x;
    int bb = bh & 7, h = bh >> 3;
    const float* xp = x + (size_t)bb * (CIN * HW) + h * W_;
#pragma unroll
    for (int j = 0; j < 32; ++j) {
        int e = threadIdx.x + 256 * j;             // 8192 = 64c * 128w
        int cc = e >> 7, ww = e & 127;
        tile[cc * 129 + ww] = __builtin_nontemporal_load(xp + cc * HW + ww);
    }
    __syncthreads();
    short* op = xt + (((size_t)(bb << 7) + h) << 13);   // [b][h][w][c]
#pragma unroll
    for (int j = 0; j < 4; ++j) {
        int t = threadIdx.x + 256 * j;             // 1024 tasks: 128w x 8 chunks
        int ww = t >> 3, c0 = (t & 7) << 3;
        short8 o;
#pragma unroll
        for (int k = 0; k < 8; ++k) o[k] = f2bf(tile[(c0 + k) * 129 + ww]);
        *(short8*)(op + ww * 64 + c0) = o;         // fully coalesced 16B stores
    }
}

// ---------- async staging: 4 rows h0-1..h0+2 of NHWC bf16 -> XOR-swizzled LDS ----------
__device__ __forceinline__ void stage4(short* A, const short* __restrict__ src,
                                       int bb, int h0, int tid) {
    int wv = tid >> 6, l = tid & 63;
    int r = wv >> 1, half = wv & 1;
    int y = h0 - 1 + r;
    int P0 = 1 + half * 64;
    int px0 = P0 + (l >> 3);                       // this lane's pixel slot
    int ckl = l & 7;                               // linear LDS chunk slot
    if ((unsigned)y < H_) {
        int ckg = ckl ^ (px0 & 7);                 // pre-swizzled source chunk
        const short* gp = src + ((((size_t)(bb << 7) + y) << 7) + (px0 - 1)) * 64 + ckg * 8;
#pragma unroll
        for (int i = 0; i < 8; ++i) {
            short* lp = &A[(r * 130 + P0 + i * 8) * 64];   // wave-uniform base
            __builtin_amdgcn_global_load_lds(
                (const __attribute__((address_space(1))) void*)(gp + i * 512),
                (__attribute__((address_space(3))) void*)lp, 16, 0, 0);
        }
    } else {                                       // out-of-range row -> zeros
        short8 z = {0, 0, 0, 0, 0, 0, 0, 0};
#pragma unroll
        for (int i = 0; i < 8; ++i)
            *(short8*)(&A[(r * 130 + P0 + i * 8) * 64 + l * 8]) = z;
    }
    if (tid < 64) {                                // zero pad cols 0,129 for all 4 rows
        int rr = tid >> 4, side = (tid >> 3) & 1, ck = tid & 7;
        int px = side * 129;
        short8 z = {0, 0, 0, 0, 0, 0, 0, 0};
        *(short8*)(&A[(rr * 130 + px) * 64 + ((ck ^ (px & 7)) << 3)]) = z;
    }
}

// ============ conv1 (offset conv): 512 thr, 2 rows, 2 blocks/CU -> offb ============
__global__ __launch_bounds__(512, 4) void k_c1(const short* __restrict__ xt,
                                               const short* __restrict__ wt1,
                                               const float* __restrict__ bof,
                                               short* __restrict__ offb) {
    __shared__ __align__(16) short lds[33280 + 6144];  // A 66,560 B + St 12,288 B
    short* A = lds;
    unsigned short* St = (unsigned short*)(lds + 33280);
    int blk = blockIdx.x, tid = threadIdx.x;       // grid 512
    int bb = blk & 7;                              // image (XCD-aligned)
    int h0 = (blk >> 3) << 1;                      // 2 output rows h0, h0+1

    stage4(A, xt, bb, h0, tid);                    // async global->LDS (swizzled)
    __syncthreads();

    int lane = tid & 63;
    int wave = tid >> 6;                           // 0..7
    int lr = wave >> 2;                            // local output row 0..1
    int p0 = (wave & 3) * 32;                      // 32 px per wave
    int m = lane & 15, quad = lane >> 4;

    f32x4 acc[2][2];
#pragma unroll
    for (int nt = 0; nt < 2; ++nt) {
        int oc = nt * 16 + m;
        float bv = (oc < 18) ? bof[oc] : 0.f;
#pragma unroll
        for (int mt = 0; mt < 2; ++mt) {
            acc[mt][nt][0] = bv; acc[mt][nt][1] = bv;
            acc[mt][nt][2] = bv; acc[mt][nt][3] = bv;
        }
    }
#pragma unroll
    for (int d = 0; d < 9; ++d) {
        int dy = d / 3, dx = d % 3;
#pragma unroll
        for (int c = 0; c < 2; ++c) {
            short8 a[2];
#pragma unroll
            for (int mt = 0; mt < 2; ++mt) {
                int px = p0 + mt * 16 + m + dx;
                a[mt] = *(const short8*)(&A[((lr + dy) * 130 + px) * 64 + (((c * 4 + quad) ^ (px & 7)) << 3)]);
            }
#pragma unroll
            for (int nt = 0; nt < 2; ++nt) {
                short8 b = *(const short8*)(wt1 + ((((d * 2 + c) * 2 + nt) * 64 + lane) << 3));
#pragma unroll
                for (int mt = 0; mt < 2; ++mt)
                    acc[mt][nt] = __builtin_amdgcn_mfma_f32_16x16x32_bf16(a[mt], b, acc[mt][nt], 0, 0, 0);
            }
        }
    }
#pragma unroll
    for (int nt = 0; nt < 2; ++nt) {
        int oc = nt * 16 + m;
        if (oc < 18) {
#pragma unroll
            for (int mt = 0; mt < 2; ++mt) {
                int pl = lr * 128 + p0 + mt * 16 + quad * 4;
#pragma unroll
                for (int r = 0; r < 4; ++r)
                    St[(pl + r) * OFFP + oc] = (unsigned short)f2bf(acc[mt][nt][r]);
            }
        }
    }
    __syncthreads();
    const unsigned* Sd = (const unsigned*)St;      // 3072 dwords
    unsigned* Od = (unsigned*)(offb + ((size_t)((bb << 14) + (h0 << 7))) * OFFP);
#pragma unroll
    for (int j = 0; j < 6; ++j)
        Od[tid + 512 * j] = Sd[tid + 512 * j];     // coalesced dword stores
}

// ---------- per-(pixel,tap) prep: local-window ids (or -1) + global ids + weights ----------
__device__ __forceinline__ void prep_task_s(int t, int tw, int th,
                                            const unsigned* __restrict__ sow,
                                            s16x4* __restrict__ idsL,
                                            s16x4* __restrict__ idsG,
                                            f32x4* __restrict__ wgs) {
    int px = (int)((unsigned)t / 9u);
    int tap = t - px * 9;
    int row = px >> 3, sx8 = px & 7;
    unsigned owk = sow[row * 96 + sx8 * 12 + tap];
    float ox = bf2f((short)(owk & 0xffff));
    float oy = bf2f((short)(owk >> 16));
    float xs = (float)((tw << 3) + sx8) + ox;
    float ys = (float)((th << 2) + row) + oy;
    float x0f = floorf(xs), y0f = floorf(ys);
    float wx1 = xs - x0f, wx0 = 1.f - wx1;
    float wy1 = ys - y0f, wy0 = 1.f - wy1;
    int x0 = (int)x0f, y0 = (int)y0f;
    int x1 = x0 + 1, y1 = y0 + 1;
    int x0c = min(max(x0, 0), W_ - 1), x1c = min(max(x1, 0), W_ - 1);
    int y0c = min(max(y0, 0), H_ - 1), y1c = min(max(y1, 0), H_ - 1);
    bool vx0 = ((unsigned)x0 < W_), vx1 = ((unsigned)x1 < W_);
    bool vy0 = ((unsigned)y0 < H_), vy1 = ((unsigned)y1 < H_);
    f32x4 wg;
    wg[0] = (vy0 && vx0) ? wy0 * wx0 : 0.f;
    wg[1] = (vy0 && vx1) ? wy0 * wx1 : 0.f;
    wg[2] = (vy1 && vx0) ? wy1 * wx0 : 0.f;
    wg[3] = (vy1 && vx1) ? wy1 * wx1 : 0.f;
    s16x4 idg;
    idg[0] = (short)(y0c * W_ + x0c);
    idg[1] = (short)(y0c * W_ + x1c);
    idg[2] = (short)(y1c * W_ + x0c);
    idg[3] = (short)(y1c * W_ + x1c);
    idsG[t] = idg;
    wgs[t] = wg;
    // window-local ids: window origin (wy0,wx0) = (th*4-3, tw*8-3), size 10x14 (stride 16)
    int wy = (th << 2) - 3, wx = (tw << 3) - 3;
    int ly0 = y0c - wy, ly1 = y1c - wy;
    int lx0 = x0c - wx, lx1 = x1c - wx;
    bool inw = ((unsigned)ly0 < 10u) && ((unsigned)ly1 < 10u) &&
               ((unsigned)lx0 < 14u) && ((unsigned)lx1 < 14u);
    s16x4 idl;
    idl[0] = (short)(inw ? (ly0 * 16 + lx0) : -1);
    idl[1] = (short)(ly0 * 16 + lx1);
    idl[2] = (short)(ly1 * 16 + lx0);
    idl[3] = (short)(ly1 * 16 + lx1);
    idsL[t] = idl;
}

// ============ deformable sample: 8x4 tile, LDS image window (10x14 px), 4 blocks/CU ============
// Gathers come from a 20.5 KB LDS window (covers |offset|<2; >99.9% of taps) with a
// per-tap global fallback -> ~14x less L1/L2 gather traffic than direct global gathers.
__global__ __launch_bounds__(256, 4) void k_samp(const short* __restrict__ xt,
                                                 const short* __restrict__ offb,
                                                 short* __restrict__ smp) {
    __shared__ unsigned sow[4 * 96];               // raw offset words, 1.5 KB
    __shared__ s16x4 idsL[288];                    // 2.25 KB  (window-local or -1)
    __shared__ s16x4 idsG[288];                    // 2.25 KB  (global clamped)
    __shared__ f32x4 wgs[288];                     // 4.5 KB
    __shared__ __align__(16) short win[10 * 16 * 64];  // 20.5 KB image window
    int blk = blockIdx.x, tid = threadIdx.x;       // 4096 blocks
    int bb = blk & 7;                              // image (XCD-aligned)
    int tile = blk >> 3;
    int tw = tile & 15, th = tile >> 4;

    {   // cooperative offset staging (stream-once)
        int rowid = tid >> 6, rl = tid & 63;
        const unsigned* srcp = (const unsigned*)(offb +
            ((size_t)((bb << 14) + (((th << 2) + rowid) << 7) + (tw << 3))) * OFFP);
        sow[rowid * 96 + rl] = __builtin_nontemporal_load(srcp + rl);
        if (rl < 32) sow[rowid * 96 + 64 + rl] = __builtin_nontemporal_load(srcp + 64 + rl);
    }

    // stage the 10x14 px window -> LDS, async, source-pre-swizzled (linear LDS dest)
    {
        int wy = (th << 2) - 3, wx = (tw << 3) - 3;
        const short* xim = xt + ((size_t)bb << 20);
#pragma unroll
        for (int it = 0; it < 5; ++it) {
            int d = tid + 256 * it;                // dest slot: [ly][lx][ck], 1280 slots
            if (d < 1280) {
                int ly = d >> 7, rem = d & 127, lx = rem >> 3, ckl = rem & 7;
                if (lx < 14) {                     // cols 14,15 unused
                    int gy = min(max(wy + ly, 0), H_ - 1);
                    int gx = min(max(wx + lx, 0), W_ - 1);
                    int ckg = ckl ^ (lx & 7);      // pre-swizzle source chunk
                    const short* gp = xim + (((size_t)gy << 7) + gx) * 64 + ckg * 8;
                    // wave-uniform LDS base; HW adds lane*16
                    short* lp = &win[((d & ~63)) * 8];
                    __builtin_amdgcn_global_load_lds(
                        (const __attribute__((address_space(1))) void*)gp,
                        (__attribute__((address_space(3))) void*)lp, 16, 0, 0);
                }
            }
        }
    }
    __syncthreads();

    // shared prep: 288 tasks = 32 px * 9 taps, each ONCE
    prep_task_s(tid, tw, th, sow, idsL, idsG, wgs);
    if (tid < 32) prep_task_s(tid + 256, tw, th, sow, idsL, idsG, wgs);
    __syncthreads();

    int lp = tid >> 3, ck = tid & 7, cko = ck * 8;
    int w = (tw << 3) + (lp & 7);
    int h = (th << 2) + (lp >> 3);
    const short* ximc = xt + ((size_t)bb << 20) + cko;
    int pb = lp * 9;

    f32x2 acc2[4];
#pragma unroll
    for (int q = 0; q < 4; ++q) { acc2[q][0] = 0.f; acc2[q][1] = 0.f; }
    // tap-major, corner-minor FMA order == previous kernels (bit-identical)
#pragma unroll
    for (int t = 0; t < 9; ++t) {
        s16x4 idl = idsL[pb + t];                  // broadcast ds_read (8 lanes/px)
        f32x4 wv = wgs[pb + t];
        short8 v[4];
        if (idl[0] >= 0) {                         // LDS window path (>99.9%)
#pragma unroll
            for (int c = 0; c < 4; ++c) {
                int pid = (int)idl[c];
                v[c] = *(const short8*)(&win[pid * 64 + ((ck ^ (pid & 7)) << 3)]);
            }
        } else {                                   // rare global fallback
            s16x4 idg = idsG[pb + t];
#pragma unroll
            for (int c = 0; c < 4; ++c)
                v[c] = *(const short8*)(ximc + (((int)idg[c]) << 6));
        }
#pragma unroll
        for (int c = 0; c < 4; ++c) {
            float wvv = wv[c];
            f32x2 wp; wp[0] = wvv; wp[1] = wvv;
            const unsigned* vd = (const unsigned*)&v[c];
#pragma unroll
            for (int q = 0; q < 4; ++q) {
                unsigned dwd = vd[q];
                f32x2 av;
                av[0] = __uint_as_float(dwd << 16);          // ch 2q
                av[1] = __uint_as_float(dwd & 0xffff0000u);  // ch 2q+1
                asm("v_pk_fma_f32 %0, %1, %2, %0" : "+v"(acc2[q]) : "v"(av), "v"(wp));
            }
        }
    }
    short8 o;
#pragma unroll
    for (int i = 0; i < 8; ++i) o[i] = f2bf(acc2[i >> 1][i & 1]);
    *(short8*)(smp + ((((size_t)(bb << 7) + h) << 7) + w) * 64 + cko) = o;
}

// ============ conv2 (regular 64-oc conv): 512 thr, 2 rows, 2 blocks/CU ============
__global__ __launch_bounds__(512, 4) void k_conv2(const short* __restrict__ smp,
                                                  const short* __restrict__ wt2,
                                                  const float* __restrict__ brg,
                                                  float* __restrict__ out) {
    __shared__ __align__(16) short A[4 * 130 * 64];    // 66,560 B
    int blk = blockIdx.x, tid = threadIdx.x;       // grid 512
    int bb = blk & 7;
    int h0 = (blk >> 3) << 1;

    stage4(A, smp, bb, h0, tid);                   // async global->LDS (swizzled)
    __syncthreads();

    int lane = tid & 63;
    int wave = tid >> 6;                           // 0..7
    int lr = wave >> 2;                            // 0..1
    int p0 = (wave & 3) * 32;
    int m = lane & 15, quad = lane >> 4;

    f32x4 acc[2][4];
#pragma unroll
    for (int nt = 0; nt < 4; ++nt) {
        float bv = brg[nt * 16 + m];
#pragma unroll
        for (int mt = 0; mt < 2; ++mt) {
            acc[mt][nt][0] = bv; acc[mt][nt][1] = bv;
            acc[mt][nt][2] = bv; acc[mt][nt][3] = bv;
        }
    }
#pragma unroll
    for (int d = 0; d < 9; ++d) {
        int dy = d / 3, dx = d % 3;
#pragma unroll
        for (int c = 0; c < 2; ++c) {
            short8 a[2];
#pragma unroll
            for (int mt = 0; mt < 2; ++mt) {
                int px = p0 + mt * 16 + m + dx;
                a[mt] = *(const short8*)(&A[((lr + dy) * 130 + px) * 64 + (((c * 4 + quad) ^ (px & 7)) << 3)]);
            }
#pragma unroll
            for (int nt = 0; nt < 4; ++nt) {
                short8 b = *(const short8*)(wt2 + ((((d * 2 + c) * 4 + nt) * 64 + lane) << 3));
#pragma unroll
                for (int mt = 0; mt < 2; ++mt)
                    acc[mt][nt] = __builtin_amdgcn_mfma_f32_16x16x32_bf16(a[mt], b, acc[mt][nt], 0, 0, 0);
            }
        }
    }
#pragma unroll
    for (int nt = 0; nt < 4; ++nt) {
        int oc = nt * 16 + m;
#pragma unroll
        for (int mt = 0; mt < 2; ++mt) {
            int wpix = p0 + mt * 16 + quad * 4;
            __builtin_nontemporal_store(acc[mt][nt],
                (f32x4*)(out + (((size_t)(bb * 64 + oc)) << 14) + ((h0 + lr) << 7) + wpix));
        }
    }
}

extern "C" void kernel_launch(void* const* d_in, const int* in_sizes, int n_in,
                              void* d_out, int out_size, void* d_ws, size_t ws_size,
                              hipStream_t stream) {
    const float* x   = (const float*)d_in[0];
    const float* wof = (const float*)d_in[1];
    const float* bof = (const float*)d_in[2];
    const float* wrg = (const float*)d_in[3];
    const float* brg = (const float*)d_in[4];
    float* out = (float*)d_out;

    char* ws = (char*)d_ws;
    short* xt   = (short*)ws;                                // 16,777,216 B
    short* smp  = (short*)(ws + 16777216);                   // 16,777,216 B
    short* offb = (short*)(ws + 2 * 16777216);               // 12,582,912 B
    short* wt1  = (short*)(ws + 2 * 16777216 + 12582912);    //     36,864 B
    short* wt2  = (short*)(ws + 2 * 16777216 + 12582912 + 36864);  // 73,728 B

    k_tr   <<<dim3(B_ * H_),           256, 0, stream>>>(x, xt, wof, wrg, wt1, wt2);
    k_c1   <<<dim3(B_ * H_ / 2),       512, 0, stream>>>(xt, wt1, bof, offb);
    k_samp <<<dim3((B_ * HW) / 32),    256, 0, stream>>>(xt, offb, smp);
    k_conv2<<<dim3(B_ * H_ / 2),       512, 0, stream>>>(smp, wt2, brg, out);
}

// Round 9
// 141.416 us; speedup vs baseline: 1.0565x; 1.0565x over previous
//
#include <hip/hip_runtime.h>

#define B_ 8
#define CIN 64
#define COUT 64
#define H_ 128
#define W_ 128
#define HW (H_*W_)
#define OFFP 24   // shorts per pixel in St (9 taps * 2 + pad -> 48B)

typedef __attribute__((ext_vector_type(8))) short short8;   // 8 bf16 (4 VGPRs)
typedef __attribute__((ext_vector_type(4))) short s16x4;    // 4 shorts
typedef __attribute__((ext_vector_type(4))) float f32x4;    // MFMA acc / weights
typedef __attribute__((ext_vector_type(2))) float f32x2;    // packed-FMA pair

__device__ __forceinline__ short f2bf(float f) {
    unsigned u = __float_as_uint(f);
    unsigned r = (u + 0x7fffu + ((u >> 16) & 1u)) >> 16;   // RNE
    return (short)r;
}
__device__ __forceinline__ float bf2f(short s) {
    return __uint_as_float(((unsigned)(unsigned short)s) << 16);
}

// ---------- weight prep: -> lane-linear bf16 frags ----------
template<int NT>
__device__ __forceinline__ void prep_one(const float* __restrict__ w, short* __restrict__ o,
                                         int i, int n_used) {
    int j = i & 7, lane = (i >> 3) & 63, rest = i >> 9;
    int nt = rest % NT, dc = rest / NT, c = dc & 1, d = dc >> 1;
    int oc = nt * 16 + (lane & 15);
    int ic = c * 32 + (lane >> 4) * 8 + j;
    float v = (oc < n_used) ? w[(oc * 64 + ic) * 9 + d] : 0.f;
    o[i] = f2bf(v);
}

// ---------- transpose x NCHW fp32 -> NHWC bf16, + weight prep folded in ----------
__global__ __launch_bounds__(256) void k_tr(const float* __restrict__ x,
                                            short* __restrict__ xt,
                                            const float* __restrict__ wof,
                                            const float* __restrict__ wrg,
                                            short* __restrict__ wt1,
                                            short* __restrict__ wt2) {
    int i = blockIdx.x * 256 + threadIdx.x;
    if (i < 9 * 2 * 2 * 512) prep_one<2>(wof, wt1, i, 18);
    if (i < 9 * 2 * 4 * 512) prep_one<4>(wrg, wt2, i, 64);

    __shared__ float tile[64 * 129];
    int bh = blockIdx.x;
    int bb = bh & 7, h = bh >> 3;
    const float* xp = x + (size_t)bb * (CIN * HW) + h * W_;
#pragma unroll
    for (int j = 0; j < 8; ++j) {                  // 2048 float4 tasks = 8192 floats
        int e = threadIdx.x + 256 * j;
        int cc = e >> 5, w4 = (e & 31) << 2;
        f32x4 v4 = __builtin_nontemporal_load((const f32x4*)(xp + cc * HW + w4));
#pragma unroll
        for (int k = 0; k < 4; ++k) tile[cc * 129 + w4 + k] = v4[k];
    }
    __syncthreads();
    short* op = xt + (((size_t)(bb << 7) + h) << 13);   // [b][h][w][c]
#pragma unroll
    for (int j = 0; j < 4; ++j) {
        int t = threadIdx.x + 256 * j;             // 1024 tasks: 128w x 8 chunks
        int ww = t >> 3, c0 = (t & 7) << 3;
        short8 o;
#pragma unroll
        for (int k = 0; k < 8; ++k) o[k] = f2bf(tile[(c0 + k) * 129 + ww]);
        *(short8*)(op + ww * 64 + c0) = o;         // fully coalesced 16B stores
    }
}

// ---------- async staging: 4 rows h0-1..h0+2 of NHWC bf16 -> XOR-swizzled LDS ----------
__device__ __forceinline__ void stage4(short* A, const short* __restrict__ src,
                                       int bb, int h0, int tid) {
    int wv = tid >> 6, l = tid & 63;
    int r = wv >> 1, half = wv & 1;
    int y = h0 - 1 + r;
    int P0 = 1 + half * 64;
    int px0 = P0 + (l >> 3);                       // this lane's pixel slot
    int ckl = l & 7;                               // linear LDS chunk slot
    if ((unsigned)y < H_) {
        int ckg = ckl ^ (px0 & 7);                 // pre-swizzled source chunk
        const short* gp = src + ((((size_t)(bb << 7) + y) << 7) + (px0 - 1)) * 64 + ckg * 8;
#pragma unroll
        for (int i = 0; i < 8; ++i) {
            short* lp = &A[(r * 130 + P0 + i * 8) * 64];   // wave-uniform base
            __builtin_amdgcn_global_load_lds(
                (const __attribute__((address_space(1))) void*)(gp + i * 512),
                (__attribute__((address_space(3))) void*)lp, 16, 0, 0);
        }
    } else {                                       // out-of-range row -> zeros
        short8 z = {0, 0, 0, 0, 0, 0, 0, 0};
#pragma unroll
        for (int i = 0; i < 8; ++i)
            *(short8*)(&A[(r * 130 + P0 + i * 8) * 64 + l * 8]) = z;
    }
    if (tid < 64) {                                // zero pad cols 0,129 for all 4 rows
        int rr = tid >> 4, side = (tid >> 3) & 1, ck = tid & 7;
        int px = side * 129;
        short8 z = {0, 0, 0, 0, 0, 0, 0, 0};
        *(short8*)(&A[(rr * 130 + px) * 64 + ((ck ^ (px & 7)) << 3)]) = z;
    }
}

// ---------- per-(pixel,tap) prep: offsets -> 4 clamped indices + 4 weights ----------
__device__ __forceinline__ void prep_task(int t, int h0,
                                          const unsigned short* __restrict__ St,
                                          s16x4* __restrict__ idxs,
                                          f32x4* __restrict__ wgs) {
    int pxl = (int)((unsigned)t / 9u);
    int tap = t - pxl * 9;
    int row = pxl >> 7, sx = pxl & 127;
    unsigned owk = *(const unsigned*)(St + pxl * OFFP + tap * 2);
    float ox = bf2f((short)(owk & 0xffff));
    float oy = bf2f((short)(owk >> 16));
    float xs = (float)sx + ox, ys = (float)(h0 + row) + oy;
    float x0f = floorf(xs), y0f = floorf(ys);
    float wx1 = xs - x0f, wx0 = 1.f - wx1;
    float wy1 = ys - y0f, wy0 = 1.f - wy1;
    int x0 = (int)x0f, y0 = (int)y0f;
    int x1 = x0 + 1, y1 = y0 + 1;
    int x0c = min(max(x0, 0), W_ - 1), x1c = min(max(x1, 0), W_ - 1);
    int y0c = min(max(y0, 0), H_ - 1), y1c = min(max(y1, 0), H_ - 1);
    bool vx0 = ((unsigned)x0 < W_), vx1 = ((unsigned)x1 < W_);
    bool vy0 = ((unsigned)y0 < H_), vy1 = ((unsigned)y1 < H_);
    f32x4 wg;
    wg[0] = (vy0 && vx0) ? wy0 * wx0 : 0.f;
    wg[1] = (vy0 && vx1) ? wy0 * wx1 : 0.f;
    wg[2] = (vy1 && vx0) ? wy1 * wx0 : 0.f;
    wg[3] = (vy1 && vx1) ? wy1 * wx1 : 0.f;
    s16x4 id;
    id[0] = (short)(y0c * W_ + x0c);
    id[1] = (short)(y0c * W_ + x1c);
    id[2] = (short)(y1c * W_ + x0c);
    id[3] = (short)(y1c * W_ + x1c);
    idxs[t] = id;
    wgs[t] = wg;
}

// ============ conv1 (offset conv) + deformable sample, fused per block ============
// 512 thr, 2 output rows, LDS 78.8 KB -> 2 blocks/CU.
__global__ __launch_bounds__(512, 4) void k_c1s(const short* __restrict__ xt,
                                                const short* __restrict__ wt1,
                                                const float* __restrict__ bof,
                                                short* __restrict__ smp) {
    __shared__ __align__(16) short lds[33280 + 6144];  // A/prep 66,560 B + St 12,288 B
    short* A = lds;
    unsigned short* St = (unsigned short*)(lds + 33280);
    int blk = blockIdx.x, tid = threadIdx.x;       // grid 512
    int bb = blk & 7;                              // image (XCD-aligned for L2 locality)
    int h0 = (blk >> 3) << 1;                      // 2 output rows h0, h0+1

    stage4(A, xt, bb, h0, tid);                    // async global->LDS (swizzled)
    __syncthreads();

    int lane = tid & 63;
    int wave = tid >> 6;                           // 0..7
    int lr = wave >> 2;                            // local output row 0..1
    int p0 = (wave & 3) * 32;                      // 32 px per wave
    int m = lane & 15, quad = lane >> 4;

    // conv1 -> offsets into St (LDS only)
    {
        f32x4 acc[2][2];
#pragma unroll
        for (int nt = 0; nt < 2; ++nt) {
            int oc = nt * 16 + m;
            float bv = (oc < 18) ? bof[oc] : 0.f;
#pragma unroll
            for (int mt = 0; mt < 2; ++mt) {
                acc[mt][nt][0] = bv; acc[mt][nt][1] = bv;
                acc[mt][nt][2] = bv; acc[mt][nt][3] = bv;
            }
        }
#pragma unroll
        for (int d = 0; d < 9; ++d) {
            int dy = d / 3, dx = d % 3;
#pragma unroll
            for (int c = 0; c < 2; ++c) {
                short8 a[2];
#pragma unroll
                for (int mt = 0; mt < 2; ++mt) {
                    int px = p0 + mt * 16 + m + dx;
                    a[mt] = *(const short8*)(&A[((lr + dy) * 130 + px) * 64 + (((c * 4 + quad) ^ (px & 7)) << 3)]);
                }
#pragma unroll
                for (int nt = 0; nt < 2; ++nt) {
                    short8 b = *(const short8*)(wt1 + ((((d * 2 + c) * 2 + nt) * 64 + lane) << 3));
#pragma unroll
                    for (int mt = 0; mt < 2; ++mt)
                        acc[mt][nt] = __builtin_amdgcn_mfma_f32_16x16x32_bf16(a[mt], b, acc[mt][nt], 0, 0, 0);
                }
            }
        }
#pragma unroll
        for (int nt = 0; nt < 2; ++nt) {
            int oc = nt * 16 + m;
            if (oc < 18) {
#pragma unroll
                for (int mt = 0; mt < 2; ++mt) {
                    int pl = lr * 128 + p0 + mt * 16 + quad * 4;
#pragma unroll
                    for (int r = 0; r < 4; ++r)
                        St[(pl + r) * OFFP + oc] = (unsigned short)f2bf(acc[mt][nt][r]);
                }
            }
        }
    }
    __syncthreads();   // St ready; A (staged input) dead beyond here

    // shared prep into dead A region: 2304 tasks = 256 px * 9 taps, each ONCE
    s16x4* idxs = (s16x4*)lds;                     // 2304 * 8 B  = 18,432 B
    f32x4* wgs  = (f32x4*)(lds + 9216);            // 2304 * 16 B = 36,864 B (tot 55.3 KB)
    {
#pragma unroll
        for (int k = 0; k < 4; ++k) prep_task(tid + 512 * k, h0, St, idxs, wgs);
        if (tid < 256) prep_task(2048 + tid, h0, St, idxs, wgs);
    }
    __syncthreads();

    // deformable bilinear sample: broadcast ds_reads of prep, pk_fma accumulate
    {
        int ck = tid & 7, sxb = tid >> 3;          // sxb 0..63
        int cko = ck * 8;
        const short* ximc = xt + ((size_t)bb << 20) + cko;
#pragma unroll
        for (int row = 0; row < 2; ++row) {
            int y = h0 + row;
#pragma unroll
            for (int hf = 0; hf < 2; ++hf) {
                int sx = sxb + hf * 64;
                int pb = (row * 128 + sx) * 9;
                f32x2 acc2[4];
#pragma unroll
                for (int q = 0; q < 4; ++q) { acc2[q][0] = 0.f; acc2[q][1] = 0.f; }
#pragma unroll
                for (int g = 0; g < 3; ++g) {      // taps 3g..3g+2
                    int eo[12]; float wf[12]; short8 v[12];
#pragma unroll
                    for (int t2 = 0; t2 < 3; ++t2) {
                        s16x4 id = idxs[pb + g * 3 + t2];
                        f32x4 wv = wgs[pb + g * 3 + t2];
#pragma unroll
                        for (int c = 0; c < 4; ++c) {
                            eo[t2 * 4 + c] = ((int)id[c]) << 6;
                            wf[t2 * 4 + c] = wv[c];
                        }
                    }
#pragma unroll
                    for (int n = 0; n < 12; ++n) v[n] = *(const short8*)(ximc + eo[n]);
#pragma unroll
                    for (int n = 0; n < 12; ++n) {
                        float wvv = wf[n];
                        f32x2 wp; wp[0] = wvv; wp[1] = wvv;
                        const unsigned* vd = (const unsigned*)&v[n];
#pragma unroll
                        for (int q = 0; q < 4; ++q) {
                            unsigned dwd = vd[q];
                            f32x2 av;
                            av[0] = __uint_as_float(dwd << 16);          // ch 2q
                            av[1] = __uint_as_float(dwd & 0xffff0000u);  // ch 2q+1
                            // 2 independent IEEE FMAs, bit-identical to scalar order
                            asm("v_pk_fma_f32 %0, %1, %2, %0" : "+v"(acc2[q]) : "v"(av), "v"(wp));
                        }
                    }
                }
                short8 o;
#pragma unroll
                for (int i = 0; i < 8; ++i) o[i] = f2bf(acc2[i >> 1][i & 1]);
                *(short8*)(smp + ((((size_t)(bb << 7) + y) << 7) + sx) * 64 + cko) = o;
            }
        }
    }
}

// ============ conv2 (regular 64-oc conv): 512 thr, 2 rows, 2 blocks/CU ============
__global__ __launch_bounds__(512, 4) void k_conv2(const short* __restrict__ smp,
                                                  const short* __restrict__ wt2,
                                                  const float* __restrict__ brg,
                                                  float* __restrict__ out) {
    __shared__ __align__(16) short A[4 * 130 * 64];    // 66,560 B
    int blk = blockIdx.x, tid = threadIdx.x;       // grid 512
    int bb = blk & 7;
    int h0 = (blk >> 3) << 1;

    stage4(A, smp, bb, h0, tid);                   // async global->LDS (swizzled)
    __syncthreads();

    int lane = tid & 63;
    int wave = tid >> 6;                           // 0..7
    int lr = wave >> 2;                            // 0..1
    int p0 = (wave & 3) * 32;
    int m = lane & 15, quad = lane >> 4;

    f32x4 acc[2][4];
#pragma unroll
    for (int nt = 0; nt < 4; ++nt) {
        float bv = brg[nt * 16 + m];
#pragma unroll
        for (int mt = 0; mt < 2; ++mt) {
            acc[mt][nt][0] = bv; acc[mt][nt][1] = bv;
            acc[mt][nt][2] = bv; acc[mt][nt][3] = bv;
        }
    }
#pragma unroll
    for (int d = 0; d < 9; ++d) {
        int dy = d / 3, dx = d % 3;
#pragma unroll
        for (int c = 0; c < 2; ++c) {
            short8 a[2];
#pragma unroll
            for (int mt = 0; mt < 2; ++mt) {
                int px = p0 + mt * 16 + m + dx;
                a[mt] = *(const short8*)(&A[((lr + dy) * 130 + px) * 64 + (((c * 4 + quad) ^ (px & 7)) << 3)]);
            }
#pragma unroll
            for (int nt = 0; nt < 4; ++nt) {
                short8 b = *(const short8*)(wt2 + ((((d * 2 + c) * 4 + nt) * 64 + lane) << 3));
#pragma unroll
                for (int mt = 0; mt < 2; ++mt)
                    acc[mt][nt] = __builtin_amdgcn_mfma_f32_16x16x32_bf16(a[mt], b, acc[mt][nt], 0, 0, 0);
            }
        }
    }
#pragma unroll
    for (int nt = 0; nt < 4; ++nt) {
        int oc = nt * 16 + m;
#pragma unroll
        for (int mt = 0; mt < 2; ++mt) {
            int wpix = p0 + mt * 16 + quad * 4;
            __builtin_nontemporal_store(acc[mt][nt],
                (f32x4*)(out + (((size_t)(bb * 64 + oc)) << 14) + ((h0 + lr) << 7) + wpix));
        }
    }
}

extern "C" void kernel_launch(void* const* d_in, const int* in_sizes, int n_in,
                              void* d_out, int out_size, void* d_ws, size_t ws_size,
                              hipStream_t stream) {
    const float* x   = (const float*)d_in[0];
    const float* wof = (const float*)d_in[1];
    const float* bof = (const float*)d_in[2];
    const float* wrg = (const float*)d_in[3];
    const float* brg = (const float*)d_in[4];
    float* out = (float*)d_out;

    char* ws = (char*)d_ws;
    short* xt  = (short*)ws;                            // 16,777,216 B
    short* smp = (short*)(ws + 16777216);               // 16,777,216 B
    short* wt1 = (short*)(ws + 2 * 16777216);           //     36,864 B
    short* wt2 = (short*)(ws + 2 * 16777216 + 36864);   //     73,728 B

    k_tr   <<<dim3(B_ * H_),     256, 0, stream>>>(x, xt, wof, wrg, wt1, wt2);
    k_c1s  <<<dim3(B_ * H_ / 2), 512, 0, stream>>>(xt, wt1, bof, smp);
    k_conv2<<<dim3(B_ * H_ / 2), 512, 0, stream>>>(smp, wt2, brg, out);
}